// Round 2
// baseline (508.155 us; speedup 1.0000x reference)
//
#include <hip/hip_runtime.h>
#include <stdint.h>

// Farthest point sampling, NPOINT=2, input [1,B,3,N] fp32 channel-major.
// Pass 1: per-batch argmax of y-channel -> f0
// Pass 2: per-batch argmax of squared dist to point f0 -> f1
// Output: int32 [B,2] = {f0, f1} per batch.

#define TPB 256   // threads per block (4 waves)
#define BPB 128   // blocks per batch for the streaming passes

typedef unsigned long long u64;

__device__ __forceinline__ u64 umax64(u64 a, u64 b) { return a > b ? a : b; }

// Monotone (order-preserving) mapping f32 -> u32.
__device__ __forceinline__ uint32_t f32_sortable(float f) {
    uint32_t b = __float_as_uint(f);
    return (b & 0x80000000u) ? ~b : (b | 0x80000000u);
}

// Encode (value, index) so that max-reduce picks max value, and on ties the
// SMALLEST index (JAX argmax first-occurrence semantics).
__device__ __forceinline__ u64 enc(float f, uint32_t idx) {
    return ((u64)f32_sortable(f) << 32) | (u64)(0xFFFFFFFFu - idx);
}

__device__ __forceinline__ int dec_idx(u64 e) {
    return (int)(0xFFFFFFFFu - (uint32_t)(e & 0xFFFFFFFFull));
}

// Block-level max reduce of per-thread u64 into s[0].
__device__ __forceinline__ u64 block_reduce_max(u64 v) {
    __shared__ u64 s[TPB];
    s[threadIdx.x] = v;
    __syncthreads();
    for (int off = TPB / 2; off > 0; off >>= 1) {
        if (threadIdx.x < off) s[threadIdx.x] = umax64(s[threadIdx.x], s[threadIdx.x + off]);
        __syncthreads();
    }
    return s[0];
}

// ---- Pass 1: partial argmax over y channel ----
__global__ __launch_bounds__(TPB) void k_argmax_y(const float* __restrict__ xyz, int N,
                                                  u64* __restrict__ part) {
    const int b  = blockIdx.x / BPB;
    const int cb = blockIdx.x % BPB;
    const float4* y4 = (const float4*)(xyz + ((size_t)b * 3 + 1) * (size_t)N);
    const int V = N >> 2;  // float4 count

    u64 best = 0;  // encodes below any real value
    for (int i = cb * TPB + threadIdx.x; i < V; i += BPB * TPB) {
        float4 v = y4[i];
        uint32_t i0 = (uint32_t)i * 4u;
        u64 e0 = enc(v.x, i0);
        u64 e1 = enc(v.y, i0 + 1);
        u64 e2 = enc(v.z, i0 + 2);
        u64 e3 = enc(v.w, i0 + 3);
        e0 = umax64(e0, e1);
        e2 = umax64(e2, e3);
        best = umax64(best, umax64(e0, e2));
    }
    u64 r = block_reduce_max(best);
    if (threadIdx.x == 0) part[blockIdx.x] = r;
}

// ---- Reduce pass-1 partials -> f0 per batch ----
__global__ __launch_bounds__(BPB) void k_reduce1(const u64* __restrict__ part,
                                                 int* __restrict__ f0) {
    const int b = blockIdx.x;
    __shared__ u64 s[BPB];
    s[threadIdx.x] = part[b * BPB + threadIdx.x];
    __syncthreads();
    for (int off = BPB / 2; off > 0; off >>= 1) {
        if (threadIdx.x < off) s[threadIdx.x] = umax64(s[threadIdx.x], s[threadIdx.x + off]);
        __syncthreads();
    }
    if (threadIdx.x == 0) f0[b] = dec_idx(s[0]);
}

// ---- Pass 2: partial argmax of squared distance to centroid f0 ----
__global__ __launch_bounds__(TPB) void k_dist(const float* __restrict__ xyz, int N,
                                              const int* __restrict__ f0,
                                              u64* __restrict__ part2) {
    const int b  = blockIdx.x / BPB;
    const int cb = blockIdx.x % BPB;
    const float* xb = xyz + (size_t)b * 3 * (size_t)N;
    const int c = f0[b];
    const float cx = xb[c];
    const float cy = xb[(size_t)N + c];
    const float cz = xb[2 * (size_t)N + c];

    const float4* x4 = (const float4*)xb;
    const float4* y4 = (const float4*)(xb + N);
    const float4* z4 = (const float4*)(xb + 2 * (size_t)N);
    const int V = N >> 2;

    u64 best = 0;
    for (int i = cb * TPB + threadIdx.x; i < V; i += BPB * TPB) {
        float4 vx = x4[i];
        float4 vy = y4[i];
        float4 vz = z4[i];
        uint32_t i0 = (uint32_t)i * 4u;

        float dx, dy, dz, d;
        dx = vx.x - cx; dy = vy.x - cy; dz = vz.x - cz;
        d = dx * dx + dy * dy + dz * dz;
        u64 e0 = enc(d, i0);
        dx = vx.y - cx; dy = vy.y - cy; dz = vz.y - cz;
        d = dx * dx + dy * dy + dz * dz;
        u64 e1 = enc(d, i0 + 1);
        dx = vx.z - cx; dy = vy.z - cy; dz = vz.z - cz;
        d = dx * dx + dy * dy + dz * dz;
        u64 e2 = enc(d, i0 + 2);
        dx = vx.w - cx; dy = vy.w - cy; dz = vz.w - cz;
        d = dx * dx + dy * dy + dz * dz;
        u64 e3 = enc(d, i0 + 3);

        e0 = umax64(e0, e1);
        e2 = umax64(e2, e3);
        best = umax64(best, umax64(e0, e2));
    }
    u64 r = block_reduce_max(best);
    if (threadIdx.x == 0) part2[blockIdx.x] = r;
}

// ---- Reduce pass-2 partials -> f1, write output ----
__global__ __launch_bounds__(BPB) void k_reduce2(const u64* __restrict__ part2,
                                                 const int* __restrict__ f0,
                                                 int* __restrict__ out) {
    const int b = blockIdx.x;
    __shared__ u64 s[BPB];
    s[threadIdx.x] = part2[b * BPB + threadIdx.x];
    __syncthreads();
    for (int off = BPB / 2; off > 0; off >>= 1) {
        if (threadIdx.x < off) s[threadIdx.x] = umax64(s[threadIdx.x], s[threadIdx.x + off]);
        __syncthreads();
    }
    if (threadIdx.x == 0) {
        out[b * 2 + 0] = f0[b];
        out[b * 2 + 1] = dec_idx(s[0]);
    }
}

extern "C" void kernel_launch(void* const* d_in, const int* in_sizes, int n_in,
                              void* d_out, int out_size, void* d_ws, size_t ws_size,
                              hipStream_t stream) {
    const float* xyz = (const float*)d_in[0];
    int* out = (int*)d_out;

    const int B = out_size / 2;                 // 32
    const int N = in_sizes[0] / (3 * B);        // 1,000,000

    // Workspace layout (all slots fully written before read; poison-safe):
    //   part1: B*BPB u64
    //   part2: B*BPB u64
    //   f0   : B int
    u64* part1 = (u64*)d_ws;
    u64* part2 = part1 + (size_t)B * BPB;
    int* f0    = (int*)(part2 + (size_t)B * BPB);

    k_argmax_y<<<B * BPB, TPB, 0, stream>>>(xyz, N, part1);
    k_reduce1<<<B, BPB, 0, stream>>>(part1, f0);
    k_dist<<<B * BPB, TPB, 0, stream>>>(xyz, N, f0, part2);
    k_reduce2<<<B, BPB, 0, stream>>>(part2, f0, out);
}